// Round 5
// baseline (235.882 us; speedup 1.0000x reference)
//
#include <hip/hip_runtime.h>
#include <math.h>

#define NN 50000
#define NE 640000
#define CAP 64   // fixed neighbor-slot capacity; Poisson(12.8) max deg ~40 << 64

typedef short short8 __attribute__((ext_vector_type(8)));   // 8 bf16 (4 VGPRs)
typedef float f32x4  __attribute__((ext_vector_type(4)));   // MFMA accumulator

// ---- bf16 helpers (RNE pack, cheap unpack) ----------------------------------
__device__ __forceinline__ unsigned bfr(float f) {
    unsigned u = __float_as_uint(f);
    return (u + 0x7FFFu + ((u >> 16) & 1u)) >> 16;
}
__device__ __forceinline__ unsigned pk2(float a, float b) { return bfr(a) | (bfr(b) << 16); }
__device__ __forceinline__ float bflo(unsigned u) { return __uint_as_float(u << 16); }
__device__ __forceinline__ float bfhi(unsigned u) { return __uint_as_float(u & 0xFFFF0000u); }

// ---- weight pack into MFMA B-frag layout (bf16) -----------------------------
__device__ __forceinline__ void packOne(const float* Wl, const float* Wr,
                                        unsigned short* wp, int idx,
                                        int CIN, int COUT) {
    int k = idx / COUT, n = idx % COUT;
    float v = (k < CIN) ? Wl[k * COUT + n] : Wr[(k - CIN) * COUT + n];
    int kt = k >> 5, quad = (k >> 3) & 3, j = k & 7;
    int nt = n >> 4, l16 = n & 15;
    int NT = COUT / 16;
    wp[(((kt * NT + nt) * 64) + quad * 16 + l16) * 8 + j] = (unsigned short)bfr(v);
}

// ============================================================================
// FUSED LAYER (R3 structure, unchanged numerics):
//   phase A: 16 groups x 16 lanes; group g aggregates rows g*8..g*8+7 into
//            LDS [128][CIN+8] (full row per group, channels lane-local).
//   phase B: two-row MFMA GEMM; agg-half of A from LDS, x-half from global.
//            Output staged in LDS, written as coalesced uint4.
//   CLS: layer-2 variant with fused classifier head.
// R5: per-layer kernels for per-phase rocprof telemetry (R4 minus the
//     k_prep store race that broke it).
// ============================================================================
template <int CIN, int COUT, bool RELU, bool CLS>
__device__ __forceinline__ void
fused_layer(const unsigned* __restrict__ Fu, const unsigned short* __restrict__ Fs,
            const int* __restrict__ nbr, const int* __restrict__ cnt,
            const unsigned short* __restrict__ Wpack, const float* __restrict__ bias,
            unsigned short* __restrict__ outp,
            const unsigned short* __restrict__ WpackC, const float* __restrict__ bc1,
            const float* __restrict__ Wc2, const float* __restrict__ bc2,
            float* __restrict__ outf,
            short* __restrict__ lds, int tile, int t) {
    constexpr int RU = CIN / 2;        // uints per feature row
    constexpr int PC = RU / 16;        // uints per lane: 2 (C=64) | 4 (C=128)
    constexpr int RS = CIN + 8;        // agg LDS row stride (shorts); 16B-aligned
    constexpr int RSu = RS / 2;        // ... in uints
    constexpr int KT = (2 * CIN) / 32;
    constexpr int NT = COUT / 16;
    constexpr int CS = 136;            // staged-output LDS stride (shorts)

    const int g = t >> 4, lg = t & 15;
    const int wave = t >> 6, lane = t & 63;
    const int quad = lane >> 4, l16 = lane & 15;

    // ---------------- phase A: aggregate 128 rows into LDS ----------------
#pragma unroll 1
    for (int i = 0; i < 8; ++i) {
        const int rloc = g * 8 + i;
        const int gw = tile * 128 + rloc;
        unsigned* lrow = (unsigned*)lds + rloc * RSu + lg * PC;
        if (gw < NN) {
            const int deg = cnt[gw];
            const int m = (deg < CAP) ? deg : CAP;
            float a[2 * PC] = {};
            for (int base = 0; base < m; base += 16) {
                int idx = NN;   // zero row: branchless padding
                if (base + lg < m) idx = nbr[gw * CAP + base + lg];
#pragma unroll
                for (int j = 0; j < 16; ++j) {
                    const int n = __shfl(idx, j, 16);
                    if (PC == 2) {
                        const uint2 u = *(const uint2*)(Fu + (size_t)n * RU + lg * 2);
                        a[0] += bflo(u.x); a[1] += bfhi(u.x);
                        a[2] += bflo(u.y); a[3] += bfhi(u.y);
                    } else {
                        const uint4 u = *(const uint4*)(Fu + (size_t)n * RU + lg * 4);
                        a[0] += bflo(u.x); a[1] += bfhi(u.x);
                        a[2] += bflo(u.y); a[3] += bfhi(u.y);
                        a[4] += bflo(u.z); a[5] += bfhi(u.z);
                        a[6] += bflo(u.w); a[7] += bfhi(u.w);
                    }
                }
            }
            const float di = 1.0f / (float)((deg > 1) ? deg : 1);
            if (PC == 2)
                *(uint2*)lrow = make_uint2(pk2(a[0] * di, a[1] * di),
                                           pk2(a[2] * di, a[3] * di));
            else
                *(uint4*)lrow = make_uint4(pk2(a[0] * di, a[1] * di),
                                           pk2(a[2] * di, a[3] * di),
                                           pk2(a[4] * di, a[5] * di),
                                           pk2(a[6] * di, a[7] * di));
        } else {
            if (PC == 2) *(uint2*)lrow = make_uint2(0u, 0u);
            else         *(uint4*)lrow = make_uint4(0u, 0u, 0u, 0u);
        }
    }
    __syncthreads();

    // ---------------- phase B: GEMM (two 16-row sets per wave) ------------
    const int rbase = tile * 128 + wave * 32;
    int r0 = rbase + l16;      if (r0 >= NN) r0 = NN - 1;
    int r1 = rbase + 16 + l16; if (r1 >= NN) r1 = NN - 1;
    const int rl0 = wave * 32 + l16, rl1 = rl0 + 16;

    f32x4 acc[2][NT] = {};
#pragma unroll
    for (int kt = 0; kt < KT; ++kt) {
        short8 a0, a1;
        if (kt < KT / 2) {
            a0 = *(const short8*)(lds + rl0 * RS + kt * 32 + quad * 8);
            a1 = *(const short8*)(lds + rl1 * RS + kt * 32 + quad * 8);
        } else {
            a0 = *(const short8*)(Fs + (size_t)r0 * CIN + (kt * 32 - CIN) + quad * 8);
            a1 = *(const short8*)(Fs + (size_t)r1 * CIN + (kt * 32 - CIN) + quad * 8);
        }
#pragma unroll
        for (int nt = 0; nt < NT; ++nt) {
            const short8 bfrag = *(const short8*)(Wpack + (size_t)((kt * NT + nt) * 64 + lane) * 8);
            acc[0][nt] = __builtin_amdgcn_mfma_f32_16x16x32_bf16(a0, bfrag, acc[0][nt], 0, 0, 0);
            acc[1][nt] = __builtin_amdgcn_mfma_f32_16x16x32_bf16(a1, bfrag, acc[1][nt], 0, 0, 0);
        }
    }
    __syncthreads();   // all waves done reading agg LDS

    if constexpr (!CLS) {
        // stage C-tile in LDS (bf16), then coalesced uint4 writeout
#pragma unroll
        for (int nt = 0; nt < NT; ++nt) {
            const float bb = bias[nt * 16 + l16];
#pragma unroll
            for (int s = 0; s < 2; ++s)
#pragma unroll
                for (int rg = 0; rg < 4; ++rg) {
                    const int rloc = wave * 32 + s * 16 + quad * 4 + rg;
                    float v = acc[s][nt][rg] + bb;
                    if (RELU) v = fmaxf(v, 0.f);
                    lds[rloc * CS + nt * 16 + l16] = (short)(unsigned short)bfr(v);
                }
        }
        __syncthreads();
        constexpr int CH = COUT / 8;   // 16B chunks per row
        for (int idx = t; idx < 128 * CH; idx += 256) {
            const int row = idx / CH, c8 = idx % CH;
            const int gr = tile * 128 + row;
            if (gr < NN)
                *(uint4*)(outp + (size_t)gr * COUT + c8 * 8) =
                    *(const uint4*)(lds + row * CS + c8 * 8);
        }
    } else {
        // CLS: stage H [128][72], classifier per-wave on its 32 rows
        constexpr int HS = 72;
#pragma unroll
        for (int nt = 0; nt < NT; ++nt) {
            const float bb = bias[nt * 16 + l16];
#pragma unroll
            for (int s = 0; s < 2; ++s)
#pragma unroll
                for (int rg = 0; rg < 4; ++rg) {
                    const int rloc = wave * 32 + s * 16 + quad * 4 + rg;
                    lds[rloc * HS + nt * 16 + l16] =
                        (short)(unsigned short)bfr(acc[s][nt][rg] + bb);
                }
        }
        __syncthreads();

        f32x4 sacc[2][2] = {};
#pragma unroll
        for (int s = 0; s < 2; ++s) {
            const int rloc = wave * 32 + s * 16 + l16;
#pragma unroll
            for (int kt2 = 0; kt2 < 2; ++kt2) {
                const short8 af = *(const short8*)(lds + rloc * HS + kt2 * 32 + quad * 8);
#pragma unroll
                for (int nt2 = 0; nt2 < 2; ++nt2) {
                    const short8 bf = *(const short8*)(WpackC + (size_t)((kt2 * 2 + nt2) * 64 + lane) * 8);
                    sacc[s][nt2] = __builtin_amdgcn_mfma_f32_16x16x32_bf16(af, bf, sacc[s][nt2], 0, 0, 0);
                }
            }
        }

        const float b1a = bc1[l16], b1b = bc1[16 + l16];
        const float w2a = Wc2[l16], w2b = Wc2[16 + l16];
        const float b2v = bc2[0];
#pragma unroll
        for (int s = 0; s < 2; ++s)
#pragma unroll
            for (int rg = 0; rg < 4; ++rg) {
                float p = fmaxf(sacc[s][0][rg] + b1a, 0.f) * w2a +
                          fmaxf(sacc[s][1][rg] + b1b, 0.f) * w2b;
#pragma unroll
                for (int off = 1; off < 16; off <<= 1) p += __shfl_xor(p, off);
                if (l16 == 0) {
                    const int row = tile * 128 + wave * 32 + s * 16 + quad * 4 + rg;
                    if (row < NN) outf[row] = 1.0f / (1.0f + expf(-(p + b2v)));
                }
            }
    }
}

// ---- per-layer kernels (one tile per block; per-phase rocprof telemetry) ----
template <int CIN, int COUT, bool RELU, bool CLS>
__global__ __launch_bounds__(256) void
k_fused(const unsigned* __restrict__ Fu, const unsigned short* __restrict__ Fs,
        const int* __restrict__ nbr, const int* __restrict__ cnt,
        const unsigned short* __restrict__ Wpack, const float* __restrict__ bias,
        unsigned short* __restrict__ outp,
        const unsigned short* __restrict__ WpackC, const float* __restrict__ bc1,
        const float* __restrict__ Wc2, const float* __restrict__ bc2,
        float* __restrict__ outf) {
    __shared__ __align__(16) short lds[128 * 136];   // 34.8 KB
    fused_layer<CIN, COUT, RELU, CLS>(Fu, Fs, nbr, cnt, Wpack, bias, outp,
                                      WpackC, bc1, Wc2, bc2, outf,
                                      lds, blockIdx.x, threadIdx.x);
}

__global__ __launch_bounds__(256) void
k_prep(const int* __restrict__ src, const int* __restrict__ dst,
       int* __restrict__ cnt, int* __restrict__ nbr,
       const float* __restrict__ x, unsigned* __restrict__ xb,
       const float* Wl0, const float* Wr0, const float* Wl1, const float* Wr1,
       const float* Wl2, const float* Wr2, const float* Wc1,
       unsigned short* wp0, unsigned short* wp1, unsigned short* wp2,
       unsigned short* wpc, unsigned short* h0b, unsigned short* h1b) {
    const int b = blockIdx.x, t = threadIdx.x;
    if (b < 2500) {
        int e = b * 256 + t;
        if (e < NE) {
            int d = dst[e];
            int p = atomicAdd(&cnt[d], 1);
            if (p < CAP) nbr[d * CAP + p] = src[e];
        }
        if (b == 0) {   // zero rows at index NN (gather targets for padding)
            if (t < 32) xb[(size_t)NN * 32 + t] = 0u;
            else if (t < 96) ((unsigned*)h0b)[(size_t)NN * 64 + (t - 32)] = 0u;
            else if (t < 160) ((unsigned*)h1b)[(size_t)NN * 64 + (t - 96)] = 0u;
        }
    } else if (b < 5625) {
        int i = (b - 2500) * 256 + t;
        if (i < NN * 16) {
            float4 v = ((const float4*)x)[i];
            ((uint2*)xb)[i] = make_uint2(pk2(v.x, v.y), pk2(v.z, v.w));
        }
    } else {
        int idx = (b - 5625) * 256 + t;
        if (idx < 16384) packOne(Wl0, Wr0, wp0, idx, 64, 128);
        else if (idx < 49152) packOne(Wl1, Wr1, wp1, idx - 16384, 128, 128);
        else if (idx < 65536) packOne(Wl2, Wr2, wp2, idx - 49152, 128, 64);
        else if (idx < 67584) packOne(Wc1, Wc1, wpc, idx - 65536, 64, 32);
    }
}

extern "C" void kernel_launch(void* const* d_in, const int* in_sizes, int n_in,
                              void* d_out, int out_size, void* d_ws, size_t ws_size,
                              hipStream_t stream) {
    const float* x   = (const float*)d_in[0];
    const int*   ei  = (const int*)d_in[1];   // [2, NE] int32
    const int*   src = ei;
    const int*   dst = ei + NE;
    const float* Wl0 = (const float*)d_in[2];
    const float* Wr0 = (const float*)d_in[3];
    const float* b0  = (const float*)d_in[4];
    const float* Wl1 = (const float*)d_in[5];
    const float* Wr1 = (const float*)d_in[6];
    const float* b1  = (const float*)d_in[7];
    const float* Wl2 = (const float*)d_in[8];
    const float* Wr2 = (const float*)d_in[9];
    const float* b2  = (const float*)d_in[10];
    const float* Wc1 = (const float*)d_in[11];
    const float* bc1 = (const float*)d_in[12];
    const float* Wc2 = (const float*)d_in[13];
    const float* bc2 = (const float*)d_in[14];
    float* out = (float*)d_out;

    char*  ws   = (char*)d_ws;
    int*   cnt  = (int*)(ws);
    unsigned short* wp0 = (unsigned short*)(ws + (size_t)256 * 1024);
    unsigned short* wp1 = (unsigned short*)(ws + (size_t)352 * 1024);
    unsigned short* wp2 = (unsigned short*)(ws + (size_t)448 * 1024);
    unsigned short* wpc = (unsigned short*)(ws + (size_t)512 * 1024);
    int*   nbr  = (int*)(ws + (size_t)1 * (1 << 20));
    unsigned short* xb   = (unsigned short*)(ws + (size_t)16 * (1 << 20));
    unsigned short* h0b  = (unsigned short*)(ws + (size_t)40 * (1 << 20));
    unsigned short* h1b  = (unsigned short*)(ws + (size_t)56 * (1 << 20));

    hipMemsetAsync(cnt, 0, (size_t)NN * sizeof(int), stream);

    const int B = 256;
    const int NTILE = (NN + 127) / 128;   // 391

    k_prep<<<5889, B, 0, stream>>>(src, dst, cnt, nbr, x, (unsigned*)xb,
                                   Wl0, Wr0, Wl1, Wr1, Wl2, Wr2, Wc1,
                                   wp0, wp1, wp2, wpc, h0b, h1b);

    // layer 0: x(64) -> h0(128)
    k_fused<64, 128, true, false><<<NTILE, B, 0, stream>>>(
        (const unsigned*)xb, xb, nbr, cnt, wp0, b0, h0b,
        nullptr, nullptr, nullptr, nullptr, nullptr);

    // layer 1: h0(128) -> h1(128)
    k_fused<128, 128, true, false><<<NTILE, B, 0, stream>>>(
        (const unsigned*)h0b, h0b, nbr, cnt, wp1, b1, h1b,
        nullptr, nullptr, nullptr, nullptr, nullptr);

    // layer 2 + classifier: h1(128) -> out
    k_fused<128, 64, false, true><<<NTILE, B, 0, stream>>>(
        (const unsigned*)h1b, h1b, nbr, cnt, wp2, b2, nullptr,
        wpc, bc1, Wc2, bc2, out);
}

// Round 6
// 216.854 us; speedup vs baseline: 1.0877x; 1.0877x over previous
//
#include <hip/hip_runtime.h>
#include <math.h>

#define NN 50000
#define NE 640000
#define CAP 64   // fixed neighbor-slot capacity; Poisson(12.8) max deg ~40 << 64
#define TM 64    // tile rows (R6: 64 -> 782 blocks, 3/CU; R2's failure was write
                 // amplification, fixed by LDS-staged coalesced writeout below)

typedef short short8 __attribute__((ext_vector_type(8)));   // 8 bf16 (4 VGPRs)
typedef float f32x4  __attribute__((ext_vector_type(4)));   // MFMA accumulator

// ---- bf16 helpers (RNE pack, cheap unpack) ----------------------------------
__device__ __forceinline__ unsigned bfr(float f) {
    unsigned u = __float_as_uint(f);
    return (u + 0x7FFFu + ((u >> 16) & 1u)) >> 16;
}
__device__ __forceinline__ unsigned pk2(float a, float b) { return bfr(a) | (bfr(b) << 16); }
__device__ __forceinline__ float bflo(unsigned u) { return __uint_as_float(u << 16); }
__device__ __forceinline__ float bfhi(unsigned u) { return __uint_as_float(u & 0xFFFF0000u); }

// ---- weight pack into MFMA B-frag layout (bf16) -----------------------------
__device__ __forceinline__ void packOne(const float* Wl, const float* Wr,
                                        unsigned short* wp, int idx,
                                        int CIN, int COUT) {
    int k = idx / COUT, n = idx % COUT;
    float v = (k < CIN) ? Wl[k * COUT + n] : Wr[(k - CIN) * COUT + n];
    int kt = k >> 5, quad = (k >> 3) & 3, j = k & 7;
    int nt = n >> 4, l16 = n & 15;
    int NT = COUT / 16;
    wp[(((kt * NT + nt) * 64) + quad * 16 + l16) * 8 + j] = (unsigned short)bfr(v);
}

// ============================================================================
// FUSED LAYER, 64-row tiles (R6):
//   phase A: 16 groups x 16 lanes; group g aggregates rows g*4..g*4+3 into
//            LDS [64][CIN+8]. Gathers are EXPLICITLY BATCHED 16-deep into
//            registers (u[16]) before accumulation -> 16 loads in flight/lane.
//   phase B: one 16-row MFMA set per wave; agg-half of A from LDS, x-half
//            from global. Output staged in LDS, written as coalesced uint4.
//   CLS: layer-2 variant with fused classifier head.
// ============================================================================
template <int CIN, int COUT, bool RELU, bool CLS>
__device__ __forceinline__ void
fused_layer(const unsigned* __restrict__ Fu, const unsigned short* __restrict__ Fs,
            const int* __restrict__ nbr, const int* __restrict__ cnt,
            const unsigned short* __restrict__ Wpack, const float* __restrict__ bias,
            unsigned short* __restrict__ outp,
            const unsigned short* __restrict__ WpackC, const float* __restrict__ bc1,
            const float* __restrict__ Wc2, const float* __restrict__ bc2,
            float* __restrict__ outf,
            short* __restrict__ lds, int tile, int t) {
    constexpr int RU = CIN / 2;        // uints per feature row
    constexpr int PC = RU / 16;        // uints per lane: 2 (C=64) | 4 (C=128)
    constexpr int RS = CIN + 8;        // agg LDS row stride (shorts); 16B-aligned
    constexpr int RSu = RS / 2;        // ... in uints
    constexpr int KT = (2 * CIN) / 32;
    constexpr int NT = COUT / 16;
    constexpr int CS = 136;            // staged-output LDS stride (shorts)

    const int g = t >> 4, lg = t & 15;
    const int wave = t >> 6, lane = t & 63;
    const int quad = lane >> 4, l16 = lane & 15;

    // ---------------- phase A: aggregate TM rows into LDS ----------------
#pragma unroll 1
    for (int i = 0; i < TM / 16; ++i) {
        const int rloc = g * (TM / 16) + i;
        const int gw = tile * TM + rloc;
        unsigned* lrow = (unsigned*)lds + rloc * RSu + lg * PC;
        if (gw < NN) {
            const int deg = cnt[gw];
            const int m = (deg < CAP) ? deg : CAP;
            float a[2 * PC] = {};
            for (int base = 0; base < m; base += 16) {
                int idx = NN;   // zero row: branchless padding
                if (base + lg < m) idx = nbr[gw * CAP + base + lg];
                if (PC == 2) {
                    uint2 u[16];
#pragma unroll
                    for (int j = 0; j < 16; ++j) {
                        const int n = __shfl(idx, j, 16);
                        u[j] = *(const uint2*)(Fu + (size_t)n * RU + lg * 2);
                    }
#pragma unroll
                    for (int j = 0; j < 16; ++j) {
                        a[0] += bflo(u[j].x); a[1] += bfhi(u[j].x);
                        a[2] += bflo(u[j].y); a[3] += bfhi(u[j].y);
                    }
                } else {
                    uint4 u[16];
#pragma unroll
                    for (int j = 0; j < 16; ++j) {
                        const int n = __shfl(idx, j, 16);
                        u[j] = *(const uint4*)(Fu + (size_t)n * RU + lg * 4);
                    }
#pragma unroll
                    for (int j = 0; j < 16; ++j) {
                        a[0] += bflo(u[j].x); a[1] += bfhi(u[j].x);
                        a[2] += bflo(u[j].y); a[3] += bfhi(u[j].y);
                        a[4] += bflo(u[j].z); a[5] += bfhi(u[j].z);
                        a[6] += bflo(u[j].w); a[7] += bfhi(u[j].w);
                    }
                }
            }
            const float di = 1.0f / (float)((deg > 1) ? deg : 1);
            if (PC == 2)
                *(uint2*)lrow = make_uint2(pk2(a[0] * di, a[1] * di),
                                           pk2(a[2] * di, a[3] * di));
            else
                *(uint4*)lrow = make_uint4(pk2(a[0] * di, a[1] * di),
                                           pk2(a[2] * di, a[3] * di),
                                           pk2(a[4] * di, a[5] * di),
                                           pk2(a[6] * di, a[7] * di));
        } else {
            if (PC == 2) *(uint2*)lrow = make_uint2(0u, 0u);
            else         *(uint4*)lrow = make_uint4(0u, 0u, 0u, 0u);
        }
    }
    __syncthreads();

    // ---------------- phase B: GEMM (one 16-row set per wave) -------------
    const int rbase = tile * TM + wave * 16;
    int r0 = rbase + l16; if (r0 >= NN) r0 = NN - 1;
    const int rl0 = wave * 16 + l16;

    f32x4 acc[NT] = {};
#pragma unroll
    for (int kt = 0; kt < KT; ++kt) {
        short8 a0;
        if (kt < KT / 2)
            a0 = *(const short8*)(lds + rl0 * RS + kt * 32 + quad * 8);
        else
            a0 = *(const short8*)(Fs + (size_t)r0 * CIN + (kt * 32 - CIN) + quad * 8);
#pragma unroll
        for (int nt = 0; nt < NT; ++nt) {
            const short8 bfrag = *(const short8*)(Wpack + (size_t)((kt * NT + nt) * 64 + lane) * 8);
            acc[nt] = __builtin_amdgcn_mfma_f32_16x16x32_bf16(a0, bfrag, acc[nt], 0, 0, 0);
        }
    }
    __syncthreads();   // all waves done reading agg LDS

    if constexpr (!CLS) {
        // stage C-tile in LDS (bf16), then coalesced uint4 writeout
#pragma unroll
        for (int nt = 0; nt < NT; ++nt) {
            const float bb = bias[nt * 16 + l16];
#pragma unroll
            for (int rg = 0; rg < 4; ++rg) {
                const int rloc = wave * 16 + quad * 4 + rg;
                float v = acc[nt][rg] + bb;
                if (RELU) v = fmaxf(v, 0.f);
                lds[rloc * CS + nt * 16 + l16] = (short)(unsigned short)bfr(v);
            }
        }
        __syncthreads();
        constexpr int CH = COUT / 8;   // 16B chunks per row
        for (int idx = t; idx < TM * CH; idx += 256) {
            const int row = idx / CH, c8 = idx % CH;
            const int gr = tile * TM + row;
            if (gr < NN)
                *(uint4*)(outp + (size_t)gr * COUT + c8 * 8) =
                    *(const uint4*)(lds + row * CS + c8 * 8);
        }
    } else {
        // CLS: stage H [64][72], classifier per-wave on its 16 rows
        constexpr int HS = 72;
#pragma unroll
        for (int nt = 0; nt < NT; ++nt) {
            const float bb = bias[nt * 16 + l16];
#pragma unroll
            for (int rg = 0; rg < 4; ++rg) {
                const int rloc = wave * 16 + quad * 4 + rg;
                lds[rloc * HS + nt * 16 + l16] =
                    (short)(unsigned short)bfr(acc[nt][rg] + bb);
            }
        }
        __syncthreads();

        f32x4 sacc[2] = {};
        const int rloc = wave * 16 + l16;
#pragma unroll
        for (int kt2 = 0; kt2 < 2; ++kt2) {
            const short8 af = *(const short8*)(lds + rloc * HS + kt2 * 32 + quad * 8);
#pragma unroll
            for (int nt2 = 0; nt2 < 2; ++nt2) {
                const short8 bf = *(const short8*)(WpackC + (size_t)((kt2 * 2 + nt2) * 64 + lane) * 8);
                sacc[nt2] = __builtin_amdgcn_mfma_f32_16x16x32_bf16(af, bf, sacc[nt2], 0, 0, 0);
            }
        }

        const float b1a = bc1[l16], b1b = bc1[16 + l16];
        const float w2a = Wc2[l16], w2b = Wc2[16 + l16];
        const float b2v = bc2[0];
#pragma unroll
        for (int rg = 0; rg < 4; ++rg) {
            float p = fmaxf(sacc[0][rg] + b1a, 0.f) * w2a +
                      fmaxf(sacc[1][rg] + b1b, 0.f) * w2b;
#pragma unroll
            for (int off = 1; off < 16; off <<= 1) p += __shfl_xor(p, off);
            if (l16 == 0) {
                const int row = tile * TM + wave * 16 + quad * 4 + rg;
                if (row < NN) outf[row] = 1.0f / (1.0f + expf(-(p + b2v)));
            }
        }
    }
}

// ---- per-layer kernels (one tile per block; per-phase rocprof telemetry) ----
template <int CIN, int COUT, bool RELU, bool CLS>
__global__ __launch_bounds__(256) void
k_fused(const unsigned* __restrict__ Fu, const unsigned short* __restrict__ Fs,
        const int* __restrict__ nbr, const int* __restrict__ cnt,
        const unsigned short* __restrict__ Wpack, const float* __restrict__ bias,
        unsigned short* __restrict__ outp,
        const unsigned short* __restrict__ WpackC, const float* __restrict__ bc1,
        const float* __restrict__ Wc2, const float* __restrict__ bc2,
        float* __restrict__ outf) {
    __shared__ __align__(16) short lds[TM * 136];   // 17.4 KB
    fused_layer<CIN, COUT, RELU, CLS>(Fu, Fs, nbr, cnt, Wpack, bias, outp,
                                      WpackC, bc1, Wc2, bc2, outf,
                                      lds, blockIdx.x, threadIdx.x);
}

__global__ __launch_bounds__(256) void
k_prep(const int* __restrict__ src, const int* __restrict__ dst,
       int* __restrict__ cnt, int* __restrict__ nbr,
       const float* __restrict__ x, unsigned* __restrict__ xb,
       const float* Wl0, const float* Wr0, const float* Wl1, const float* Wr1,
       const float* Wl2, const float* Wr2, const float* Wc1,
       unsigned short* wp0, unsigned short* wp1, unsigned short* wp2,
       unsigned short* wpc, unsigned short* h0b, unsigned short* h1b) {
    const int b = blockIdx.x, t = threadIdx.x;
    if (b < 2500) {
        int e = b * 256 + t;
        if (e < NE) {
            int d = dst[e];
            int p = atomicAdd(&cnt[d], 1);
            if (p < CAP) nbr[d * CAP + p] = src[e];
        }
        if (b == 0) {   // zero rows at index NN (gather targets for padding)
            if (t < 32) xb[(size_t)NN * 32 + t] = 0u;
            else if (t < 96) ((unsigned*)h0b)[(size_t)NN * 64 + (t - 32)] = 0u;
            else if (t < 160) ((unsigned*)h1b)[(size_t)NN * 64 + (t - 96)] = 0u;
        }
    } else if (b < 5625) {
        int i = (b - 2500) * 256 + t;
        if (i < NN * 16) {
            float4 v = ((const float4*)x)[i];
            ((uint2*)xb)[i] = make_uint2(pk2(v.x, v.y), pk2(v.z, v.w));
        }
    } else {
        int idx = (b - 5625) * 256 + t;
        if (idx < 16384) packOne(Wl0, Wr0, wp0, idx, 64, 128);
        else if (idx < 49152) packOne(Wl1, Wr1, wp1, idx - 16384, 128, 128);
        else if (idx < 65536) packOne(Wl2, Wr2, wp2, idx - 49152, 128, 64);
        else if (idx < 67584) packOne(Wc1, Wc1, wpc, idx - 65536, 64, 32);
    }
}

extern "C" void kernel_launch(void* const* d_in, const int* in_sizes, int n_in,
                              void* d_out, int out_size, void* d_ws, size_t ws_size,
                              hipStream_t stream) {
    const float* x   = (const float*)d_in[0];
    const int*   ei  = (const int*)d_in[1];   // [2, NE] int32
    const int*   src = ei;
    const int*   dst = ei + NE;
    const float* Wl0 = (const float*)d_in[2];
    const float* Wr0 = (const float*)d_in[3];
    const float* b0  = (const float*)d_in[4];
    const float* Wl1 = (const float*)d_in[5];
    const float* Wr1 = (const float*)d_in[6];
    const float* b1  = (const float*)d_in[7];
    const float* Wl2 = (const float*)d_in[8];
    const float* Wr2 = (const float*)d_in[9];
    const float* b2  = (const float*)d_in[10];
    const float* Wc1 = (const float*)d_in[11];
    const float* bc1 = (const float*)d_in[12];
    const float* Wc2 = (const float*)d_in[13];
    const float* bc2 = (const float*)d_in[14];
    float* out = (float*)d_out;

    char*  ws   = (char*)d_ws;
    int*   cnt  = (int*)(ws);
    unsigned short* wp0 = (unsigned short*)(ws + (size_t)256 * 1024);
    unsigned short* wp1 = (unsigned short*)(ws + (size_t)352 * 1024);
    unsigned short* wp2 = (unsigned short*)(ws + (size_t)448 * 1024);
    unsigned short* wpc = (unsigned short*)(ws + (size_t)512 * 1024);
    int*   nbr  = (int*)(ws + (size_t)1 * (1 << 20));
    unsigned short* xb   = (unsigned short*)(ws + (size_t)16 * (1 << 20));
    unsigned short* h0b  = (unsigned short*)(ws + (size_t)40 * (1 << 20));
    unsigned short* h1b  = (unsigned short*)(ws + (size_t)56 * (1 << 20));

    hipMemsetAsync(cnt, 0, (size_t)NN * sizeof(int), stream);

    const int B = 256;
    const int NTILE = (NN + TM - 1) / TM;   // 782

    k_prep<<<5889, B, 0, stream>>>(src, dst, cnt, nbr, x, (unsigned*)xb,
                                   Wl0, Wr0, Wl1, Wr1, Wl2, Wr2, Wc1,
                                   wp0, wp1, wp2, wpc, h0b, h1b);

    // layer 0: x(64) -> h0(128)
    k_fused<64, 128, true, false><<<NTILE, B, 0, stream>>>(
        (const unsigned*)xb, xb, nbr, cnt, wp0, b0, h0b,
        nullptr, nullptr, nullptr, nullptr, nullptr);

    // layer 1: h0(128) -> h1(128)
    k_fused<128, 128, true, false><<<NTILE, B, 0, stream>>>(
        (const unsigned*)h0b, h0b, nbr, cnt, wp1, b1, h1b,
        nullptr, nullptr, nullptr, nullptr, nullptr);

    // layer 2 + classifier: h1(128) -> out
    k_fused<128, 64, false, true><<<NTILE, B, 0, stream>>>(
        (const unsigned*)h1b, h1b, nbr, cnt, wp2, b2, nullptr,
        wpc, bc1, Wc2, bc2, out);
}